// Round 7
// baseline (492.189 us; speedup 1.0000x reference)
//
#include <hip/hip_runtime.h>
#include <float.h>

// Problem geometry
#define DI   64
#define DOUT 62
#define CI   3
#define CO   16
#define NB   16
constexpr int SP   = DOUT * DOUT * DOUT;      // 238328
constexpr int HBLK = 16;                      // ceil(62/4)
constexpr int NBLK = HBLK * DOUT;             // 992 partial blocks per n

// Module-owned scratch (BSS): fully rewritten every call.
__device__ float g_psum[NB * CO * NBLK];
__device__ float g_psq [NB * CO * NBLK];
__device__ float g_stats[NB * CO * 2];

// 16-channel cross-correlation conv (lax.conv_general_dilated semantics):
// y[o,d,h,w] = sum_{i,p,q,r} x[i, d+p, h+q, w+r] * W[o, i, p, q, r]
__device__ __forceinline__ void conv16(const float* __restrict__ x,
                                       const float* __restrict__ w,
                                       int n, int d, int h, int tx,
                                       float acc[CO])
{
    const float* xn = x + (size_t)n * CI * DI * DI * DI;
#pragma unroll
    for (int i = 0; i < CI; ++i) {
#pragma unroll
        for (int kd = 0; kd < 3; ++kd) {
#pragma unroll
            for (int kh = 0; kh < 3; ++kh) {
                const float* row = xn + (((i * DI) + (d + kd)) * DI + (h + kh)) * DI + tx;
                float x0 = row[0], x1 = row[1], x2 = row[2];
                const int off = i * 27 + kd * 9 + kh * 3;
#pragma unroll
                for (int o = 0; o < CO; ++o) {
                    const float* wo = w + o * 81 + off;
                    acc[o] = fmaf(x0, wo[0], acc[o]);
                    acc[o] = fmaf(x1, wo[1], acc[o]);
                    acc[o] = fmaf(x2, wo[2], acc[o]);
                }
            }
        }
    }
}

// Pass 1: conv + bias + m, deterministic per-block partial sums.
// block (64,4): tx = w, ty = wave; grid (16, 62, 16) = (hblk, d, n)
__global__ __launch_bounds__(256) void pass1_kernel(
    const float* __restrict__ x, const float* __restrict__ w,
    const float* __restrict__ b, const float* __restrict__ m)
{
    const int tx = threadIdx.x;
    const int ty = threadIdx.y;
    const int h  = blockIdx.x * 4 + ty;
    const int d  = blockIdx.y;
    const int n  = blockIdx.z;
    const bool active = (tx < DOUT) && (h < DOUT);

    float acc[CO];
#pragma unroll
    for (int o = 0; o < CO; ++o) acc[o] = 0.f;
    if (active) conv16(x, w, n, d, h, tx, acc);

    __shared__ float redS[4][CO];
    __shared__ float redQ[4][CO];

#pragma unroll
    for (int o = 0; o < CO; ++o) {
        float v = active ? (acc[o] + b[o]) * m[o] : 0.f;
        float s = v, q = v * v;
#pragma unroll
        for (int off = 32; off > 0; off >>= 1) {
            s += __shfl_down(s, off);
            q += __shfl_down(q, off);
        }
        if (tx == 0) { redS[ty][o] = s; redQ[ty][o] = q; }
    }
    __syncthreads();

    if (ty == 0 && tx < CO) {
        const int o = tx;
        float s = redS[0][o] + redS[1][o] + redS[2][o] + redS[3][o];
        float q = redQ[0][o] + redQ[1][o] + redQ[2][o] + redQ[3][o];
        const int blk = blockIdx.x + HBLK * blockIdx.y;   // 0..991
        g_psum[(n * CO + o) * NBLK + blk] = s;
        g_psq [(n * CO + o) * NBLK + blk] = q;
    }
}

// Reduce 992 partials per (n,c) -> mean, invstd
__global__ __launch_bounds__(256) void finalize_stats_kernel()
{
    const int idx = blockIdx.x;             // n*16 + o
    const int tid = threadIdx.x;
    const float* ps = g_psum + (size_t)idx * NBLK;
    const float* pq = g_psq  + (size_t)idx * NBLK;
    float s = 0.f, q = 0.f;
    for (int i = tid; i < NBLK; i += 256) { s += ps[i]; q += pq[i]; }
    __shared__ float ls[256], lq[256];
    ls[tid] = s; lq[tid] = q;
    __syncthreads();
    for (int off = 128; off > 0; off >>= 1) {
        if (tid < off) { ls[tid] += ls[tid + off]; lq[tid] += lq[tid + off]; }
        __syncthreads();
    }
    if (tid == 0) {
        const float inv_n = 1.0f / (float)SP;
        float mean = ls[0] * inv_n;
        float var  = fmaxf(lq[0] * inv_n - mean * mean, 0.f);
        g_stats[idx * 2 + 0] = mean;
        g_stats[idx * 2 + 1] = rsqrtf(var + 1e-5f);
    }
}

// Pass 2: recompute conv, normalize, clamp, *m, channel-max, write FP32
__global__ __launch_bounds__(256) void pass2_kernel(
    const float* __restrict__ x, const float* __restrict__ w,
    const float* __restrict__ b, const float* __restrict__ m,
    float* __restrict__ out)
{
    const int tx = threadIdx.x;
    const int h  = blockIdx.x * 4 + threadIdx.y;
    const int d  = blockIdx.y;
    const int n  = blockIdx.z;
    if (tx >= DOUT || h >= DOUT) return;
    const int sp = (d * DOUT + h) * DOUT + tx;

    float acc[CO];
#pragma unroll
    for (int o = 0; o < CO; ++o) acc[o] = 0.f;
    conv16(x, w, n, d, h, tx, acc);

    float mx = -FLT_MAX;
#pragma unroll
    for (int o = 0; o < CO; ++o) {
        const float mu = g_stats[(n * CO + o) * 2 + 0];
        const float is = g_stats[(n * CO + o) * 2 + 1];
        float v = (acc[o] + b[o]) * m[o];
        v = (v - mu) * is;
        v = fminf(fmaxf(v, -1.f), 1.f) * m[o];
        mx = fmaxf(mx, v);
    }
    out[(size_t)n * SP + sp] = mx;   // fp32 — the reference's true output dtype
}

extern "C" void kernel_launch(void* const* d_in, const int* in_sizes, int n_in,
                              void* d_out, int out_size, void* d_ws, size_t ws_size,
                              hipStream_t stream)
{
    // Input order proven by R2==R3==R4 bit-identity: {x, w, b, m}, fp32.
    const float* x = (const float*)d_in[0];
    const float* w = (const float*)d_in[1];
    const float* b = (const float*)d_in[2];
    const float* m = (const float*)d_in[3];
    float* out = (float*)d_out;

    const dim3 blk(64, 4);
    const dim3 grd(HBLK, DOUT, NB);
    pass1_kernel<<<grd, blk, 0, stream>>>(x, w, b, m);
    finalize_stats_kernel<<<dim3(NB * CO), dim3(256), 0, stream>>>();
    pass2_kernel<<<grd, blk, 0, stream>>>(x, w, b, m, out);
}

// Round 8
// 335.601 us; speedup vs baseline: 1.4666x; 1.4666x over previous
//
#include <hip/hip_runtime.h>
#include <float.h>

// Geometry
#define DI   64
#define DOUT 62
#define CI   3
#define CO   16
#define NB   16
constexpr int SP    = DOUT * DOUT * DOUT;   // 238328
constexpr int HBLK  = 16;                   // h tiles of 4
constexpr int DBLK  = 16;                   // d tiles of 4
constexpr int NPART = HBLK * DBLK;          // 256 partials per (n,c)

// Module BSS scratch (fully rewritten every call)
__device__ float g_psum[NB * CO * NPART];
__device__ float g_psq [NB * CO * NPART];
__device__ float g_stats[NB * CO * 2];

// ---------------------------------------------------------------------------
// Tiled conv: block (64,4) computes a [4d][4h][62w] x 16ch tile.
// LDS slab: x[i][p][hr][w] : 3*6*6*64 floats = 27.6 KB.
// Each thread: acc[4 d][16 ch]; 162 LDS reads vs 5184 FMAs.
// ---------------------------------------------------------------------------
template <int MODE>  // 0 = pass1 (stats only), 1 = pass1+store y, 2 = pass2 recompute->out
__global__ __launch_bounds__(256, 4) void conv_kernel(
    const float* __restrict__ x, const float* __restrict__ wgt,
    const float* __restrict__ b, const float* __restrict__ m,
    float* __restrict__ yout)   // MODE1: y buffer; MODE2: final out
{
    const int tx = threadIdx.x;              // w lane 0..63
    const int ty = threadIdx.y;              // 0..3
    const int h0 = blockIdx.x * 4;
    const int d0 = blockIdx.y * 4;
    const int n  = blockIdx.z;
    const int h  = h0 + ty;

    __shared__ float xs[3 * 6 * 6 * 64];     // ((i*6+p)*6+hr)*64 + w

    // Stage slab (clamped at the top edges; clamped rows feed only masked outputs)
    const float* xn = x + (size_t)n * CI * DI * DI * DI;
    for (int rr = ty; rr < 108; rr += 4) {
        const int i  = rr / 36;
        const int rm = rr % 36;
        const int dg = min(d0 + rm / 6, DI - 1);
        const int hg = min(h0 + rm % 6, DI - 1);
        xs[rr * 64 + tx] = xn[((i * DI + dg) * DI + hg) * DI + tx];
    }
    __syncthreads();

    const bool active = (tx < DOUT) && (h < DOUT);

    float acc[4][CO];
#pragma unroll
    for (int dd = 0; dd < 4; ++dd)
#pragma unroll
        for (int o = 0; o < CO; ++o) acc[dd][o] = 0.f;

    if (active) {
#pragma unroll
        for (int i = 0; i < CI; ++i) {
#pragma unroll
            for (int kh = 0; kh < 3; ++kh) {
                const float* rowp = xs + (i * 36 + ty + kh) * 64 + tx;
#pragma unroll
                for (int p = 0; p < 6; ++p) {
                    const float x0 = rowp[p * 384 + 0];
                    const float x1 = rowp[p * 384 + 1];
                    const float x2 = rowp[p * 384 + 2];
#pragma unroll
                    for (int kd = 0; kd < 3; ++kd) {
                        const int dd = p - kd;
                        if (dd < 0 || dd > 3) continue;
                        const float* wp = wgt + i * 27 + kd * 9 + kh * 3;
#pragma unroll
                        for (int o = 0; o < CO; ++o) {
                            acc[dd][o] = fmaf(x0, wp[o * 81 + 0], acc[dd][o]);
                            acc[dd][o] = fmaf(x1, wp[o * 81 + 1], acc[dd][o]);
                            acc[dd][o] = fmaf(x2, wp[o * 81 + 2], acc[dd][o]);
                        }
                    }
                }
            }
        }
    }

    if (MODE == 2) {
        // normalize, clamp, *m, channel-max, store fp32
        if (active) {
            float mx[4] = { -FLT_MAX, -FLT_MAX, -FLT_MAX, -FLT_MAX };
#pragma unroll
            for (int o = 0; o < CO; ++o) {
                const float mu = g_stats[(n * CO + o) * 2 + 0];
                const float is = g_stats[(n * CO + o) * 2 + 1];
                const float bo = b[o], mo = m[o];
#pragma unroll
                for (int dd = 0; dd < 4; ++dd) {
                    float v = (acc[dd][o] + bo) * mo;
                    v = (v - mu) * is;
                    v = fminf(fmaxf(v, -1.f), 1.f) * mo;
                    mx[dd] = fmaxf(mx[dd], v);
                }
            }
#pragma unroll
            for (int dd = 0; dd < 4; ++dd)
                if (d0 + dd < DOUT)
                    yout[(size_t)n * SP + ((d0 + dd) * DOUT + h) * DOUT + tx] = mx[dd];
        }
        return;
    }

    // MODE 0/1: bias+m, optional y store, block-level sum/sumsq partials
    __shared__ float redS[4][CO];
    __shared__ float redQ[4][CO];

#pragma unroll
    for (int o = 0; o < CO; ++o) {
        float s = 0.f, q = 0.f;
        if (active) {
            const float bo = b[o], mo = m[o];
#pragma unroll
            for (int dd = 0; dd < 4; ++dd) {
                if (d0 + dd < DOUT) {
                    const float v = (acc[dd][o] + bo) * mo;
                    s += v; q += v * v;
                    if (MODE == 1)
                        yout[(size_t)(n * CO + o) * SP + ((d0 + dd) * DOUT + h) * DOUT + tx] = v;
                }
            }
        }
#pragma unroll
        for (int off = 32; off > 0; off >>= 1) {
            s += __shfl_down(s, off);
            q += __shfl_down(q, off);
        }
        if (tx == 0) { redS[ty][o] = s; redQ[ty][o] = q; }
    }
    __syncthreads();

    if (ty == 0 && tx < CO) {
        const int o = tx;
        const float s = redS[0][o] + redS[1][o] + redS[2][o] + redS[3][o];
        const float q = redQ[0][o] + redQ[1][o] + redQ[2][o] + redQ[3][o];
        const int blk = blockIdx.x + HBLK * blockIdx.y;      // 0..255
        g_psum[(n * CO + o) * NPART + blk] = s;
        g_psq [(n * CO + o) * NPART + blk] = q;
    }
}

// Reduce 256 partials per (n,c) -> mean, invstd
__global__ __launch_bounds__(256) void finalize_stats_kernel()
{
    const int idx = blockIdx.x;              // n*16 + o
    const int tid = threadIdx.x;
    float s = g_psum[idx * NPART + tid];
    float q = g_psq [idx * NPART + tid];
    __shared__ float ls[256], lq[256];
    ls[tid] = s; lq[tid] = q;
    __syncthreads();
    for (int off = 128; off > 0; off >>= 1) {
        if (tid < off) { ls[tid] += ls[tid + off]; lq[tid] += lq[tid + off]; }
        __syncthreads();
    }
    if (tid == 0) {
        const float inv_n = 1.0f / (float)SP;
        const float mean = ls[0] * inv_n;
        const float var  = fmaxf(lq[0] * inv_n - mean * mean, 0.f);
        g_stats[idx * 2 + 0] = mean;
        g_stats[idx * 2 + 1] = rsqrtf(var + 1e-5f);
    }
}

// Memory-bound pass 2 when y was stored: read y, normalize, clamp, *m, max, store
__global__ __launch_bounds__(256) void pass2_ry_kernel(
    const float* __restrict__ y, const float* __restrict__ m,
    float* __restrict__ out)
{
    const int gid = blockIdx.x * 256 + threadIdx.x;
    if (gid >= NB * SP) return;
    const int n  = gid / SP;
    const int sp = gid % SP;

    float mx = -FLT_MAX;
#pragma unroll
    for (int o = 0; o < CO; ++o) {
        const float mu = g_stats[(n * CO + o) * 2 + 0];
        const float is = g_stats[(n * CO + o) * 2 + 1];
        float v = y[(size_t)(n * CO + o) * SP + sp];
        v = (v - mu) * is;
        v = fminf(fmaxf(v, -1.f), 1.f) * m[o];
        mx = fmaxf(mx, v);
    }
    out[gid] = mx;
}

extern "C" void kernel_launch(void* const* d_in, const int* in_sizes, int n_in,
                              void* d_out, int out_size, void* d_ws, size_t ws_size,
                              hipStream_t stream)
{
    const float* x = (const float*)d_in[0];
    const float* w = (const float*)d_in[1];
    const float* b = (const float*)d_in[2];
    const float* m = (const float*)d_in[3];
    float* out = (float*)d_out;

    const dim3 blk(64, 4);
    const dim3 grd(HBLK, DBLK, NB);
    const size_t yBytes = (size_t)NB * CO * SP * sizeof(float);   // ~244 MB

    if (ws_size >= yBytes) {
        float* y = (float*)d_ws;
        conv_kernel<1><<<grd, blk, 0, stream>>>(x, w, b, m, y);
        finalize_stats_kernel<<<dim3(NB * CO), dim3(256), 0, stream>>>();
        pass2_ry_kernel<<<dim3((NB * SP + 255) / 256), dim3(256), 0, stream>>>(y, m, out);
    } else {
        conv_kernel<0><<<grd, blk, 0, stream>>>(x, w, b, m, nullptr);
        finalize_stats_kernel<<<dim3(NB * CO), dim3(256), 0, stream>>>();
        conv_kernel<2><<<grd, blk, 0, stream>>>(x, w, b, m, out);
    }
}